// Round 1
// baseline (1621.112 us; speedup 1.0000x reference)
//
#include <hip/hip_runtime.h>
#include <cstddef>

#define NT   8
#define NN   100000
#define NE   1600000
#define DIN  64
#define DH   64
#define DE   16
#define FLAT 4096
#define BN   1024

__device__ __forceinline__ void atomAdd(float* p, float v) { unsafeAtomicAdd(p, v); }

__device__ __forceinline__ void fma4(float4& a, float s, const float4& w) {
  a.x = fmaf(s, w.x, a.x); a.y = fmaf(s, w.y, a.y);
  a.z = fmaf(s, w.z, a.z); a.w = fmaf(s, w.w, a.w);
}

// ---------------- init: w[1]=init_w, zero k/acc1, deg=1 (self-loop) ----------------
__global__ void k_init(const float* __restrict__ init_w, float* __restrict__ wbuf,
                       float* __restrict__ kbuf, float* __restrict__ acc1,
                       float* __restrict__ deg) {
  int i = blockIdx.x * blockDim.x + threadIdx.x;          // 32768 threads
  if (i < FLAT) wbuf[FLAT + i] = init_w[i];
  if (i < 8 * FLAT) kbuf[i] = 0.f;
  if (i < 2 * BN) acc1[i] = 0.f;
  for (int n = i; n < NN; n += gridDim.x * blockDim.x) deg[n] = 1.0f;
}

// ---------------- ODE phase A: acc1[pe] += win @ w1 (tile-split, atomics) ----------
// win = wbase + c0*k0 + c1*k1 + c2*k2 + c3*k3  (k* from kbase block)
// also zeroes k_zero (this stage's B-target) and acc_zero (other-parity acc1).
__global__ __launch_bounds__(256) void k_odeA(
    const float* __restrict__ w1, const float* __restrict__ wbase,
    const float* __restrict__ kbase, float c0, float c1, float c2, float c3,
    float* __restrict__ acc_dst, float* __restrict__ acc_zero,
    float* __restrict__ k_zero, float* __restrict__ w_store) {
  __shared__ float win[256];
  __shared__ float red[256];
  const int t = threadIdx.x;
  const int ic = blockIdx.x & 15, jc = blockIdx.x >> 4;   // 16 i-chunks x 16 j-chunks
  const int i0 = ic * 256;
  if (t < 16) k_zero[blockIdx.x * 16 + t] = 0.f;          // 256*16 = 4096
  if (t >= 16 && t < 20) acc_zero[blockIdx.x * 4 + (t - 16)] = 0.f;  // 256*4 = 1024
  {
    int i = i0 + t;
    float v = wbase[i] + c0 * kbase[i] + c1 * kbase[FLAT + i]
            + c2 * kbase[2 * FLAT + i] + c3 * kbase[3 * FLAT + i];
    win[t] = v;
    if (w_store != nullptr && jc == 0) w_store[i] = v;    // single-writer w_next
  }
  __syncthreads();
  const int jl = t & 63, ig = t >> 6;
  const int j = jc * 64 + jl;
  const float* wp = w1 + (size_t)(i0 + ig * 64) * BN + j;
  float acc = 0.f;
#pragma unroll 8
  for (int ii = 0; ii < 64; ++ii)
    acc = fmaf(win[ig * 64 + ii], wp[(size_t)ii * BN], acc);
  red[t] = acc;
  __syncthreads();
  if (t < 64) {
    float s = red[t] + red[t + 64] + red[t + 128] + red[t + 192];
    atomAdd(&acc_dst[jc * 64 + t], s);
  }
}

// ---------------- ODE phase B: k_dst += tanh(acc1+b1) @ w2 (+b2 once) --------------
__global__ __launch_bounds__(256) void k_odeB(
    const float* __restrict__ w2, const float* __restrict__ acc_src,
    const float* __restrict__ b1, const float* __restrict__ b2,
    float* __restrict__ k_dst) {
  __shared__ float tl[64];
  const int t = threadIdx.x;
  const int ic = blockIdx.x & 15, jc = blockIdx.x >> 4;
  const int i0 = ic * 64;
  if (t < 64) tl[t] = tanhf(acc_src[i0 + t] + b1[i0 + t]);
  __syncthreads();
  const int j = jc * 256 + t;
  const float* wp = w2 + (size_t)i0 * FLAT + j;
  float acc = (ic == 0) ? b2[j] : 0.f;
#pragma unroll 8
  for (int ii = 0; ii < 64; ++ii)
    acc = fmaf(tl[ii], wp[(size_t)ii * FLAT], acc);
  atomAdd(&k_dst[j], acc);
}

// ---------------- final W_T = w[0] + h/8*(k1 + 3(k2+k3) + k4) (step-6 parity 0) ----
__global__ void k_final(const float* __restrict__ w0, const float* __restrict__ k0,
                        float* __restrict__ WT) {
  int i = blockIdx.x * blockDim.x + threadIdx.x;
  if (i < FLAT) {
    const float h8 = (1.0f / 7.0f) * 0.125f;
    WT[i] = w0[i] + h8 * (k0[i] + 3.f * (k0[FLAT + i] + k0[2 * FLAT + i]) + k0[3 * FLAT + i]);
  }
}

// ---------------- degree (in-degree by col, self-loop via init deg=1) --------------
__global__ void k_deg(const int* __restrict__ ei, float* __restrict__ deg) {
  int e = blockIdx.x * blockDim.x + threadIdx.x;
  if (e < NE) atomAdd(&deg[ei[NE + e]], 1.0f);
}

__global__ void k_dis(float* __restrict__ deg) {
  int i = blockIdx.x * blockDim.x + threadIdx.x;
  if (i < NN) deg[i] = rsqrtf(deg[i]);   // deg >= 1 always
}

// ---------------- xw = x_last @ W_T : 16 lanes/node, 4 nodes/thread-group ----------
__global__ __launch_bounds__(256) void k_xw(
    const float* __restrict__ x_last, const float* __restrict__ WT,
    float* __restrict__ xw) {
  __shared__ float wt[FLAT];
  for (int i = threadIdx.x; i < FLAT; i += 256) wt[i] = WT[i];
  __syncthreads();
  const int lane = threadIdx.x & 15;
  const int grp = threadIdx.x >> 4;
  const int n0 = blockIdx.x * 64 + grp * 4;
  if (n0 >= NN) return;
  const int nvalid = (NN - n0 < 4) ? (NN - n0) : 4;
  const float4* xp[4];
#pragma unroll
  for (int m = 0; m < 4; ++m) {
    int n = (m < nvalid) ? (n0 + m) : n0;
    xp[m] = (const float4*)(x_last + (size_t)n * 64);
  }
  float4 acc[4];
#pragma unroll
  for (int m = 0; m < 4; ++m) acc[m] = make_float4(0.f, 0.f, 0.f, 0.f);
#pragma unroll
  for (int q = 0; q < 16; ++q) {
    const float* wr = &wt[(q * 4) * 64 + lane * 4];
    float4 w0 = *(const float4*)&wr[0];
    float4 w1 = *(const float4*)&wr[64];
    float4 w2 = *(const float4*)&wr[128];
    float4 w3 = *(const float4*)&wr[192];
#pragma unroll
    for (int m = 0; m < 4; ++m) {
      float4 x4 = xp[m][q];          // same addr across 16 lanes -> broadcast
      fma4(acc[m], x4.x, w0); fma4(acc[m], x4.y, w1);
      fma4(acc[m], x4.z, w2); fma4(acc[m], x4.w, w3);
    }
  }
  for (int m = 0; m < nvalid; ++m)
    *(float4*)&xw[(size_t)(n0 + m) * 64 + lane * 4] = acc[m];
}

// ---------------- scatter: h[col] += dis[row]*dis[col]*xw[row] ---------------------
__global__ __launch_bounds__(256) void k_scatter(
    const int* __restrict__ ei, const float* __restrict__ dis,
    const float* __restrict__ xw, float* __restrict__ hacc) {
  const int e = blockIdx.x * 4 + (threadIdx.x >> 6);
  const int lane = threadIdx.x & 63;
  if (e >= NE) return;
  int row = ei[e], col = ei[NE + e];
  float norm = dis[row] * dis[col];
  float v = norm * xw[(size_t)row * 64 + lane];
  atomAdd(&hacc[(size_t)col * 64 + lane], v);
}

// ---------------- finalize: hrelu = relu(hacc + dis^2*xw); A=hrelu@W1a (in place),
//                  B=hrelu@W1b. 16 lanes/node, 4 nodes per lane-group. -------------
__global__ __launch_bounds__(256) void k_finalize(
    const float* __restrict__ mlp_w1, const float* __restrict__ dis,
    const float* __restrict__ xw, float* __restrict__ hA, float* __restrict__ Bb) {
  __shared__ float wa[FLAT];
  __shared__ float wb[FLAT];
  for (int i = threadIdx.x; i < FLAT; i += 256) {
    wa[i] = mlp_w1[i];
    wb[i] = mlp_w1[FLAT + i];
  }
  __syncthreads();
  const int lane = threadIdx.x & 15;
  const int grp = threadIdx.x >> 4;
  const int n0 = blockIdx.x * 64 + grp * 4;
  if (n0 >= NN) return;
  const int nvalid = (NN - n0 < 4) ? (NN - n0) : 4;
  float d2[4];
  const float4* hp[4];
  const float4* xp[4];
#pragma unroll
  for (int m = 0; m < 4; ++m) {
    int n = (m < nvalid) ? (n0 + m) : n0;
    float d = dis[n];
    d2[m] = d * d;
    hp[m] = (const float4*)(hA + (size_t)n * 64);
    xp[m] = (const float4*)(xw + (size_t)n * 64);
  }
  float4 aA[4], aB[4];
#pragma unroll
  for (int m = 0; m < 4; ++m) { aA[m] = make_float4(0,0,0,0); aB[m] = make_float4(0,0,0,0); }
#pragma unroll
  for (int q = 0; q < 16; ++q) {
    const float* war = &wa[(q * 4) * 64 + lane * 4];
    const float* wbr = &wb[(q * 4) * 64 + lane * 4];
    float4 wa0 = *(const float4*)&war[0];
    float4 wa1 = *(const float4*)&war[64];
    float4 wa2 = *(const float4*)&war[128];
    float4 wa3 = *(const float4*)&war[192];
    float4 wb0 = *(const float4*)&wbr[0];
    float4 wb1 = *(const float4*)&wbr[64];
    float4 wb2 = *(const float4*)&wbr[128];
    float4 wb3 = *(const float4*)&wbr[192];
#pragma unroll
    for (int m = 0; m < 4; ++m) {
      float4 h4 = hp[m][q];
      float4 x4 = xp[m][q];
      float v0 = fmaxf(fmaf(d2[m], x4.x, h4.x), 0.f);
      float v1 = fmaxf(fmaf(d2[m], x4.y, h4.y), 0.f);
      float v2 = fmaxf(fmaf(d2[m], x4.z, h4.z), 0.f);
      float v3 = fmaxf(fmaf(d2[m], x4.w, h4.w), 0.f);
      fma4(aA[m], v0, wa0); fma4(aA[m], v1, wa1); fma4(aA[m], v2, wa2); fma4(aA[m], v3, wa3);
      fma4(aB[m], v0, wb0); fma4(aB[m], v1, wb1); fma4(aB[m], v2, wb2); fma4(aB[m], v3, wb3);
    }
  }
  for (int m = 0; m < nvalid; ++m) {
    *(float4*)&hA[(size_t)(n0 + m) * 64 + lane * 4] = aA[m];   // wave-lockstep: reads done
    *(float4*)&Bb[(size_t)(n0 + m) * 64 + lane * 4] = aB[m];
  }
}

// ---------------- edge MLP: out = relu(A[row]+B[col]+ea@W1c+b1) @ w2 + b2 ----------
// W1c columns held in registers; grid-stride so the register load amortizes.
__global__ __launch_bounds__(256) void k_edge(
    const int* __restrict__ ei, const float* __restrict__ A, const float* __restrict__ B,
    const float* __restrict__ eattr, const float* __restrict__ mlp_w1,
    const float* __restrict__ mlp_b1, const float* __restrict__ mlp_w2,
    const float* __restrict__ mlp_b2, float* __restrict__ out) {
  const int lane = threadIdx.x & 15;
  float4 wc[16];
#pragma unroll
  for (int f = 0; f < 16; ++f)
    wc[f] = *(const float4*)&mlp_w1[(size_t)(128 + f) * 64 + lane * 4];
  const float4 b1v = *(const float4*)&mlp_b1[lane * 4];
  const float4 w2v = *(const float4*)&mlp_w2[lane * 4];
  const float b2v = mlp_b2[0];
  const long stride = (long)gridDim.x * 16;
  for (long e = (long)blockIdx.x * 16 + (threadIdx.x >> 4); e < NE; e += stride) {
    int row = ei[e], col = ei[NE + e];
    float4 a4 = *(const float4*)&A[(size_t)row * 64 + lane * 4];
    float4 b4 = *(const float4*)&B[(size_t)col * 64 + lane * 4];
    const float4* ep = (const float4*)&eattr[(size_t)e * 16];
    float4 e0 = ep[0], e1 = ep[1], e2 = ep[2], e3 = ep[3];
    float4 acc;
    acc.x = a4.x + b4.x + b1v.x;
    acc.y = a4.y + b4.y + b1v.y;
    acc.z = a4.z + b4.z + b1v.z;
    acc.w = a4.w + b4.w + b1v.w;
    fma4(acc, e0.x, wc[0]);  fma4(acc, e0.y, wc[1]);  fma4(acc, e0.z, wc[2]);  fma4(acc, e0.w, wc[3]);
    fma4(acc, e1.x, wc[4]);  fma4(acc, e1.y, wc[5]);  fma4(acc, e1.z, wc[6]);  fma4(acc, e1.w, wc[7]);
    fma4(acc, e2.x, wc[8]);  fma4(acc, e2.y, wc[9]);  fma4(acc, e2.z, wc[10]); fma4(acc, e2.w, wc[11]);
    fma4(acc, e3.x, wc[12]); fma4(acc, e3.y, wc[13]); fma4(acc, e3.z, wc[14]); fma4(acc, e3.w, wc[15]);
    float p = fmaxf(acc.x, 0.f) * w2v.x + fmaxf(acc.y, 0.f) * w2v.y
            + fmaxf(acc.z, 0.f) * w2v.z + fmaxf(acc.w, 0.f) * w2v.w;
    p += __shfl_xor(p, 1, 16);
    p += __shfl_xor(p, 2, 16);
    p += __shfl_xor(p, 4, 16);
    p += __shfl_xor(p, 8, 16);
    if (lane == 0) out[e] = p + b2v;
  }
}

extern "C" void kernel_launch(void* const* d_in, const int* in_sizes, int n_in,
                              void* d_out, int out_size, void* d_ws, size_t ws_size,
                              hipStream_t stream) {
  (void)in_sizes; (void)n_in; (void)out_size; (void)ws_size;
  const float* x_seq  = (const float*)d_in[0];
  const float* eattr  = (const float*)d_in[1];
  const float* init_w = (const float*)d_in[2];
  const float* ode_w1 = (const float*)d_in[3];
  const float* ode_b1 = (const float*)d_in[4];
  const float* ode_w2 = (const float*)d_in[5];
  const float* ode_b2 = (const float*)d_in[6];
  const float* mlp_w1 = (const float*)d_in[7];
  const float* mlp_b1 = (const float*)d_in[8];
  const float* mlp_w2 = (const float*)d_in[9];
  const float* mlp_b2 = (const float*)d_in[10];
  const int*   eidx   = (const int*)d_in[11];
  float* out = (float*)d_out;

  float* ws   = (float*)d_ws;
  float* wbuf = ws;                         // [2][FLAT]
  float* kbuf = wbuf + 2 * FLAT;            // [2][4][FLAT]
  float* acc1 = kbuf + 8 * FLAT;            // [2][BN]
  float* WT   = acc1 + 2 * BN;              // [FLAT]
  float* deg  = ws + 49152;                 // [NN] -> becomes dis in place
  float* xw   = ws + 152576;                // [NN*64]
  float* hA   = xw + (size_t)NN * 64;       // [NN*64] scatter accum -> A in place
  float* Bb   = hA + (size_t)NN * 64;       // [NN*64]
  // total ~77.4 MB of ws

  hipMemsetAsync(hA, 0, (size_t)NN * 64 * sizeof(float), stream);
  k_init<<<128, 256, 0, stream>>>(init_w, wbuf, kbuf, acc1, deg);
  k_deg<<<(NE + 255) / 256, 256, 0, stream>>>(eidx, deg);
  k_dis<<<(NN + 255) / 256, 256, 0, stream>>>(deg);

  const float h = 1.0f / 7.0f;
  for (int s = 0; s < 7; ++s) {
    int p = s & 1;
    for (int c = 0; c < 4; ++c) {
      int ev = s * 4 + c, pe = ev & 1;
      float c0, c1, c2, c3;
      const float* wb;
      float* wst = nullptr;
      int kp;
      if (c == 0) {          // k1 eval at w_next(prev step); also stores w[p]
        c0 = h * 0.125f; c1 = 3.f * h * 0.125f; c2 = c1; c3 = c0;
        wb = wbuf + (1 - p) * FLAT; kp = 1 - p; wst = wbuf + p * FLAT;
      } else if (c == 1) {   // w + h*k1/3
        c0 = h / 3.f; c1 = 0.f; c2 = 0.f; c3 = 0.f; wb = wbuf + p * FLAT; kp = p;
      } else if (c == 2) {   // w + h*(k2 - k1/3)
        c0 = -h / 3.f; c1 = h; c2 = 0.f; c3 = 0.f; wb = wbuf + p * FLAT; kp = p;
      } else {               // w + h*(k1 - k2 + k3)
        c0 = h; c1 = -h; c2 = h; c3 = 0.f; wb = wbuf + p * FLAT; kp = p;
      }
      k_odeA<<<256, 256, 0, stream>>>(ode_w1, wb, kbuf + (size_t)kp * 4 * FLAT,
                                      c0, c1, c2, c3,
                                      acc1 + pe * BN, acc1 + (1 - pe) * BN,
                                      kbuf + (size_t)(p * 4 + c) * FLAT, wst);
      k_odeB<<<256, 256, 0, stream>>>(ode_w2, acc1 + pe * BN, ode_b1, ode_b2,
                                      kbuf + (size_t)(p * 4 + c) * FLAT);
    }
  }
  k_final<<<16, 256, 0, stream>>>(wbuf, kbuf, WT);   // step 6 has parity 0
  k_xw<<<(NN + 63) / 64, 256, 0, stream>>>(x_seq + (size_t)(NT - 1) * NN * DIN, WT, xw);
  k_scatter<<<NE / 4, 256, 0, stream>>>(eidx, deg, xw, hA);
  k_finalize<<<(NN + 63) / 64, 256, 0, stream>>>(mlp_w1, deg, xw, hA, Bb);
  k_edge<<<8192, 256, 0, stream>>>(eidx, hA, Bb, eattr, mlp_w1, mlp_b1, mlp_w2, mlp_b2, out);
}

// Round 2
// 1545.036 us; speedup vs baseline: 1.0492x; 1.0492x over previous
//
#include <hip/hip_runtime.h>
#include <cstddef>

#define NT   8
#define NN   100000
#define NE   1600000
#define DIN  64
#define DH   64
#define DE   16
#define FLAT 4096
#define BN   1024

__device__ __forceinline__ void atomAdd(float* p, float v) { unsafeAtomicAdd(p, v); }

__device__ __forceinline__ void fma4(float4& a, float s, const float4& w) {
  a.x = fmaf(s, w.x, a.x); a.y = fmaf(s, w.y, a.y);
  a.z = fmaf(s, w.z, a.z); a.w = fmaf(s, w.w, a.w);
}

// ---------------- init: w[1]=init_w, zero k/acc1, zero cnt -------------------------
__global__ void k_init(const float* __restrict__ init_w, float* __restrict__ wbuf,
                       float* __restrict__ kbuf, float* __restrict__ acc1,
                       int* __restrict__ cnt) {
  int i = blockIdx.x * blockDim.x + threadIdx.x;          // 32768 threads
  if (i < FLAT) wbuf[FLAT + i] = init_w[i];
  if (i < 8 * FLAT) kbuf[i] = 0.f;
  if (i < 2 * BN) acc1[i] = 0.f;
  for (int n = i; n < NN; n += gridDim.x * blockDim.x) cnt[n] = 0;
}

// ---------------- ODE phase A: acc1[pe] += win @ w1 (tile-split, atomics) ----------
__global__ __launch_bounds__(256) void k_odeA(
    const float* __restrict__ w1, const float* __restrict__ wbase,
    const float* __restrict__ kbase, float c0, float c1, float c2, float c3,
    float* __restrict__ acc_dst, float* __restrict__ acc_zero,
    float* __restrict__ k_zero, float* __restrict__ w_store) {
  __shared__ float win[256];
  __shared__ float red[256];
  const int t = threadIdx.x;
  const int ic = blockIdx.x & 15, jc = blockIdx.x >> 4;   // 16 i-chunks x 16 j-chunks
  const int i0 = ic * 256;
  if (t < 16) k_zero[blockIdx.x * 16 + t] = 0.f;          // 256*16 = 4096
  if (t >= 16 && t < 20) acc_zero[blockIdx.x * 4 + (t - 16)] = 0.f;  // 256*4 = 1024
  {
    int i = i0 + t;
    float v = wbase[i] + c0 * kbase[i] + c1 * kbase[FLAT + i]
            + c2 * kbase[2 * FLAT + i] + c3 * kbase[3 * FLAT + i];
    win[t] = v;
    if (w_store != nullptr && jc == 0) w_store[i] = v;    // single-writer w_next
  }
  __syncthreads();
  const int jl = t & 63, ig = t >> 6;
  const int j = jc * 64 + jl;
  const float* wp = w1 + (size_t)(i0 + ig * 64) * BN + j;
  float acc = 0.f;
#pragma unroll 8
  for (int ii = 0; ii < 64; ++ii)
    acc = fmaf(win[ig * 64 + ii], wp[(size_t)ii * BN], acc);
  red[t] = acc;
  __syncthreads();
  if (t < 64) {
    float s = red[t] + red[t + 64] + red[t + 128] + red[t + 192];
    atomAdd(&acc_dst[jc * 64 + t], s);
  }
}

// ---------------- ODE phase B: k_dst += tanh(acc1+b1) @ w2 (+b2 once) --------------
__global__ __launch_bounds__(256) void k_odeB(
    const float* __restrict__ w2, const float* __restrict__ acc_src,
    const float* __restrict__ b1, const float* __restrict__ b2,
    float* __restrict__ k_dst) {
  __shared__ float tl[64];
  const int t = threadIdx.x;
  const int ic = blockIdx.x & 15, jc = blockIdx.x >> 4;
  const int i0 = ic * 64;
  if (t < 64) tl[t] = tanhf(acc_src[i0 + t] + b1[i0 + t]);
  __syncthreads();
  const int j = jc * 256 + t;
  const float* wp = w2 + (size_t)i0 * FLAT + j;
  float acc = (ic == 0) ? b2[j] : 0.f;
#pragma unroll 8
  for (int ii = 0; ii < 64; ++ii)
    acc = fmaf(tl[ii], wp[(size_t)ii * FLAT], acc);
  atomAdd(&k_dst[j], acc);
}

// ---------------- final W_T ---------------------------------------------------------
__global__ void k_final(const float* __restrict__ w0, const float* __restrict__ k0,
                        float* __restrict__ WT) {
  int i = blockIdx.x * blockDim.x + threadIdx.x;
  if (i < FLAT) {
    const float h8 = (1.0f / 7.0f) * 0.125f;
    WT[i] = w0[i] + h8 * (k0[i] + 3.f * (k0[FLAT + i] + k0[2 * FLAT + i]) + k0[3 * FLAT + i]);
  }
}

// ---------------- CSR build: histogram by col --------------------------------------
__global__ void k_hist(const int* __restrict__ ei, int* __restrict__ cnt) {
  int e = blockIdx.x * blockDim.x + threadIdx.x;
  if (e < NE) atomicAdd(&cnt[ei[NE + e]], 1);
}

// ---------------- scan step 1: per-block exclusive scan of cnt ---------------------
__global__ __launch_bounds__(256) void k_scan1(const int* __restrict__ cnt,
                                               int* __restrict__ offs,
                                               int* __restrict__ bsum) {
  __shared__ int s[256];
  const int t = threadIdx.x;
  const int i = blockIdx.x * 256 + t;
  int v = (i < NN) ? cnt[i] : 0;
  s[t] = v;
  __syncthreads();
  for (int off = 1; off < 256; off <<= 1) {
    int x = (t >= off) ? s[t - off] : 0;
    __syncthreads();
    s[t] += x;
    __syncthreads();
  }
  if (i < NN) offs[i] = s[t] - v;          // exclusive
  if (t == 255) bsum[blockIdx.x] = s[255];
}

// ---------------- scan step 2: scan of block sums (single block) -------------------
__global__ __launch_bounds__(512) void k_scan2(int* __restrict__ bsum,
                                               int* __restrict__ bofs, int nblk) {
  __shared__ int s[512];
  const int t = threadIdx.x;
  int v = (t < nblk) ? bsum[t] : 0;
  s[t] = v;
  __syncthreads();
  for (int off = 1; off < 512; off <<= 1) {
    int x = (t >= off) ? s[t - off] : 0;
    __syncthreads();
    s[t] += x;
    __syncthreads();
  }
  if (t < nblk) bofs[t] = s[t] - v;        // exclusive
}

// ---------------- scan step 3: add block offsets, init cursors, dis ----------------
__global__ __launch_bounds__(256) void k_scan3(const int* __restrict__ cnt,
                                               int* __restrict__ offs,
                                               const int* __restrict__ bofs,
                                               int* __restrict__ cur,
                                               float* __restrict__ dis) {
  const int i = blockIdx.x * 256 + threadIdx.x;
  if (i < NN) {
    int o = offs[i] + bofs[i >> 8];
    offs[i] = o;
    cur[i] = o;
    dis[i] = rsqrtf((float)(cnt[i] + 1));  // +1 self-loop, deg >= 1 always
  }
  if (i == 0) offs[NN] = NE;
}

// ---------------- CSR fill: csr[pos] = (row, edge_id), bucketed by col -------------
__global__ void k_fill(const int* __restrict__ ei, int* __restrict__ cur,
                       int2* __restrict__ csr) {
  int e = blockIdx.x * blockDim.x + threadIdx.x;
  if (e < NE) {
    int row = ei[e], col = ei[NE + e];
    int pos = atomicAdd(&cur[col], 1);
    csr[pos] = make_int2(row, e);
  }
}

// ---------------- xw = x_last @ W_T : 16 lanes/node, 4 nodes/thread-group ----------
__global__ __launch_bounds__(256) void k_xw(
    const float* __restrict__ x_last, const float* __restrict__ WT,
    float* __restrict__ xw) {
  __shared__ float wt[FLAT];
  for (int i = threadIdx.x; i < FLAT; i += 256) wt[i] = WT[i];
  __syncthreads();
  const int lane = threadIdx.x & 15;
  const int grp = threadIdx.x >> 4;
  const int n0 = blockIdx.x * 64 + grp * 4;
  if (n0 >= NN) return;
  const int nvalid = (NN - n0 < 4) ? (NN - n0) : 4;
  const float4* xp[4];
#pragma unroll
  for (int m = 0; m < 4; ++m) {
    int n = (m < nvalid) ? (n0 + m) : n0;
    xp[m] = (const float4*)(x_last + (size_t)n * 64);
  }
  float4 acc[4];
#pragma unroll
  for (int m = 0; m < 4; ++m) acc[m] = make_float4(0.f, 0.f, 0.f, 0.f);
#pragma unroll
  for (int q = 0; q < 16; ++q) {
    const float* wr = &wt[(q * 4) * 64 + lane * 4];
    float4 w0 = *(const float4*)&wr[0];
    float4 w1 = *(const float4*)&wr[64];
    float4 w2 = *(const float4*)&wr[128];
    float4 w3 = *(const float4*)&wr[192];
#pragma unroll
    for (int m = 0; m < 4; ++m) {
      float4 x4 = xp[m][q];          // same addr across 16 lanes -> broadcast
      fma4(acc[m], x4.x, w0); fma4(acc[m], x4.y, w1);
      fma4(acc[m], x4.z, w2); fma4(acc[m], x4.w, w3);
    }
  }
  for (int m = 0; m < nvalid; ++m)
    *(float4*)&xw[(size_t)(n0 + m) * 64 + lane * 4] = acc[m];
}

// ---------------- pass 1: h[col] = relu(sum_e norm*xw[row] + d^2*xw[col]) ----------
// one 64-lane wave per node, lane = feature index; pure gather, no atomics.
__global__ __launch_bounds__(256) void k_gh(
    const int* __restrict__ offs, const int2* __restrict__ csr,
    const float* __restrict__ dis, const float* __restrict__ xw,
    float* __restrict__ h) {
  const int node = blockIdx.x * 4 + (threadIdx.x >> 6);
  const int lane = threadIdx.x & 63;
  if (node >= NN) return;
  const int off0 = offs[node], off1 = offs[node + 1];
  const float d = dis[node];
  float acc = d * d * xw[(size_t)node * 64 + lane];
  int e = off0;
  for (; e + 1 < off1; e += 2) {
    int2 c0 = csr[e], c1 = csr[e + 1];
    float n0 = d * dis[c0.x], n1 = d * dis[c1.x];
    float x0 = xw[(size_t)c0.x * 64 + lane];
    float x1 = xw[(size_t)c1.x * 64 + lane];
    acc = fmaf(n0, x0, acc);
    acc = fmaf(n1, x1, acc);
  }
  if (e < off1) {
    int2 c0 = csr[e];
    acc = fmaf(d * dis[c0.x], xw[(size_t)c0.x * 64 + lane], acc);
  }
  h[(size_t)node * 64 + lane] = fmaxf(acc, 0.f);
}

// ---------------- finalize: A = h@W1a (in place over h), B = h@W1b -----------------
__global__ __launch_bounds__(256) void k_finalize(
    const float* __restrict__ mlp_w1, float* __restrict__ hA,
    float* __restrict__ Bb) {
  __shared__ float wa[FLAT];
  __shared__ float wb[FLAT];
  for (int i = threadIdx.x; i < FLAT; i += 256) {
    wa[i] = mlp_w1[i];
    wb[i] = mlp_w1[FLAT + i];
  }
  __syncthreads();
  const int lane = threadIdx.x & 15;
  const int grp = threadIdx.x >> 4;
  const int n0 = blockIdx.x * 64 + grp * 4;
  if (n0 >= NN) return;
  const int nvalid = (NN - n0 < 4) ? (NN - n0) : 4;
  const float4* hp[4];
#pragma unroll
  for (int m = 0; m < 4; ++m) {
    int n = (m < nvalid) ? (n0 + m) : n0;
    hp[m] = (const float4*)(hA + (size_t)n * 64);
  }
  float4 aA[4], aB[4];
#pragma unroll
  for (int m = 0; m < 4; ++m) { aA[m] = make_float4(0,0,0,0); aB[m] = make_float4(0,0,0,0); }
#pragma unroll
  for (int q = 0; q < 16; ++q) {
    const float* war = &wa[(q * 4) * 64 + lane * 4];
    const float* wbr = &wb[(q * 4) * 64 + lane * 4];
    float4 wa0 = *(const float4*)&war[0];
    float4 wa1 = *(const float4*)&war[64];
    float4 wa2 = *(const float4*)&war[128];
    float4 wa3 = *(const float4*)&war[192];
    float4 wb0 = *(const float4*)&wbr[0];
    float4 wb1 = *(const float4*)&wbr[64];
    float4 wb2 = *(const float4*)&wbr[128];
    float4 wb3 = *(const float4*)&wbr[192];
#pragma unroll
    for (int m = 0; m < 4; ++m) {
      float4 h4 = hp[m][q];
      fma4(aA[m], h4.x, wa0); fma4(aA[m], h4.y, wa1); fma4(aA[m], h4.z, wa2); fma4(aA[m], h4.w, wa3);
      fma4(aB[m], h4.x, wb0); fma4(aB[m], h4.y, wb1); fma4(aB[m], h4.z, wb2); fma4(aB[m], h4.w, wb3);
    }
  }
  for (int m = 0; m < nvalid; ++m) {
    *(float4*)&hA[(size_t)(n0 + m) * 64 + lane * 4] = aA[m];   // wave-lockstep: reads done
    *(float4*)&Bb[(size_t)(n0 + m) * 64 + lane * 4] = aB[m];
  }
}

// ---------------- pass 2: edge MLP via CSR, B[col]+b1 register-resident ------------
// one 64-lane wave per node (col), lane = hidden unit; walks incoming edges.
__global__ __launch_bounds__(256) void k_emlp(
    const int* __restrict__ offs, const int2* __restrict__ csr,
    const float* __restrict__ A, const float* __restrict__ B,
    const float* __restrict__ eattr, const float* __restrict__ mlp_w1,
    const float* __restrict__ mlp_b1, const float* __restrict__ mlp_w2,
    const float* __restrict__ mlp_b2, float* __restrict__ out) {
  const int node = blockIdx.x * 4 + (threadIdx.x >> 6);
  const int lane = threadIdx.x & 63;
  if (node >= NN) return;
  // per-lane W1c column (16 values) + w2 + (B[col]+b1)
  float wc[16];
#pragma unroll
  for (int f = 0; f < 16; ++f) wc[f] = mlp_w1[(size_t)(128 + f) * 64 + lane];
  const float w2l = mlp_w2[lane];
  const float b2v = mlp_b2[0];
  const float bc = B[(size_t)node * 64 + lane] + mlp_b1[lane];
  const int off0 = offs[node], off1 = offs[node + 1];

  for (int e = off0; e < off1; ++e) {
    int2 ce = csr[e];
    float av = A[(size_t)ce.x * 64 + lane];
    const float4* ep = (const float4*)(eattr + (size_t)ce.y * 16);  // broadcast loads
    float4 e0 = ep[0], e1 = ep[1], e2 = ep[2], e3 = ep[3];
    float acc = av + bc;
    acc = fmaf(e0.x, wc[0], acc);  acc = fmaf(e0.y, wc[1], acc);
    acc = fmaf(e0.z, wc[2], acc);  acc = fmaf(e0.w, wc[3], acc);
    acc = fmaf(e1.x, wc[4], acc);  acc = fmaf(e1.y, wc[5], acc);
    acc = fmaf(e1.z, wc[6], acc);  acc = fmaf(e1.w, wc[7], acc);
    acc = fmaf(e2.x, wc[8], acc);  acc = fmaf(e2.y, wc[9], acc);
    acc = fmaf(e2.z, wc[10], acc); acc = fmaf(e2.w, wc[11], acc);
    acc = fmaf(e3.x, wc[12], acc); acc = fmaf(e3.y, wc[13], acc);
    acc = fmaf(e3.z, wc[14], acc); acc = fmaf(e3.w, wc[15], acc);
    float p = fmaxf(acc, 0.f) * w2l;
    p += __shfl_xor(p, 1);
    p += __shfl_xor(p, 2);
    p += __shfl_xor(p, 4);
    p += __shfl_xor(p, 8);
    p += __shfl_xor(p, 16);
    p += __shfl_xor(p, 32);
    if (lane == 0) out[ce.y] = p + b2v;
  }
}

extern "C" void kernel_launch(void* const* d_in, const int* in_sizes, int n_in,
                              void* d_out, int out_size, void* d_ws, size_t ws_size,
                              hipStream_t stream) {
  (void)in_sizes; (void)n_in; (void)out_size; (void)ws_size;
  const float* x_seq  = (const float*)d_in[0];
  const float* eattr  = (const float*)d_in[1];
  const float* init_w = (const float*)d_in[2];
  const float* ode_w1 = (const float*)d_in[3];
  const float* ode_b1 = (const float*)d_in[4];
  const float* ode_w2 = (const float*)d_in[5];
  const float* ode_b2 = (const float*)d_in[6];
  const float* mlp_w1 = (const float*)d_in[7];
  const float* mlp_b1 = (const float*)d_in[8];
  const float* mlp_w2 = (const float*)d_in[9];
  const float* mlp_b2 = (const float*)d_in[10];
  const int*   eidx   = (const int*)d_in[11];
  float* out = (float*)d_out;

  float* ws   = (float*)d_ws;
  float* wbuf = ws;                          // [2][FLAT]
  float* kbuf = wbuf + 2 * FLAT;             // [2][4][FLAT]
  float* acc1 = kbuf + 8 * FLAT;             // [2][BN]
  float* WT   = acc1 + 2 * BN;               // [FLAT]
  float* dis  = ws + 49152;                  // [NN]
  int*   cnt  = (int*)(ws + 149152);         // [NN]
  int*   offs = (int*)(ws + 249152);         // [NN+1]
  int*   bsum = (int*)(ws + 349184);         // [512]
  int*   bofs = (int*)(ws + 349696);         // [512]
  int*   cur  = (int*)(ws + 350208);         // [NN]
  int2*  csr  = (int2*)(ws + 450560);        // [NE] (row, eid)
  float* xw   = ws + 450560 + 2 * (size_t)NE;  // [NN*64]; becomes B after finalize
  float* hA   = xw + (size_t)NN * 64;        // [NN*64]: h -> A in place
  // total ~66 MB of ws

  const int nblk_n = (NN + 255) / 256;       // 391

  k_init<<<128, 256, 0, stream>>>(init_w, wbuf, kbuf, acc1, cnt);
  k_hist<<<(NE + 255) / 256, 256, 0, stream>>>(eidx, cnt);
  k_scan1<<<nblk_n, 256, 0, stream>>>(cnt, offs, bsum);
  k_scan2<<<1, 512, 0, stream>>>(bsum, bofs, nblk_n);
  k_scan3<<<nblk_n, 256, 0, stream>>>(cnt, offs, bofs, cur, dis);
  k_fill<<<(NE + 255) / 256, 256, 0, stream>>>(eidx, cur, csr);

  const float h = 1.0f / 7.0f;
  for (int s = 0; s < 7; ++s) {
    int p = s & 1;
    for (int c = 0; c < 4; ++c) {
      int ev = s * 4 + c, pe = ev & 1;
      float c0, c1, c2, c3;
      const float* wb;
      float* wst = nullptr;
      int kp;
      if (c == 0) {          // k1 eval at w_next(prev step); also stores w[p]
        c0 = h * 0.125f; c1 = 3.f * h * 0.125f; c2 = c1; c3 = c0;
        wb = wbuf + (1 - p) * FLAT; kp = 1 - p; wst = wbuf + p * FLAT;
      } else if (c == 1) {   // w + h*k1/3
        c0 = h / 3.f; c1 = 0.f; c2 = 0.f; c3 = 0.f; wb = wbuf + p * FLAT; kp = p;
      } else if (c == 2) {   // w + h*(k2 - k1/3)
        c0 = -h / 3.f; c1 = h; c2 = 0.f; c3 = 0.f; wb = wbuf + p * FLAT; kp = p;
      } else {               // w + h*(k1 - k2 + k3)
        c0 = h; c1 = -h; c2 = h; c3 = 0.f; wb = wbuf + p * FLAT; kp = p;
      }
      k_odeA<<<256, 256, 0, stream>>>(ode_w1, wb, kbuf + (size_t)kp * 4 * FLAT,
                                      c0, c1, c2, c3,
                                      acc1 + pe * BN, acc1 + (1 - pe) * BN,
                                      kbuf + (size_t)(p * 4 + c) * FLAT, wst);
      k_odeB<<<256, 256, 0, stream>>>(ode_w2, acc1 + pe * BN, ode_b1, ode_b2,
                                      kbuf + (size_t)(p * 4 + c) * FLAT);
    }
  }
  k_final<<<16, 256, 0, stream>>>(wbuf, kbuf, WT);   // step 6 has parity 0

  k_xw<<<(NN + 63) / 64, 256, 0, stream>>>(x_seq + (size_t)(NT - 1) * NN * DIN, WT, xw);
  k_gh<<<(NN + 3) / 4, 256, 0, stream>>>(offs, csr, dis, xw, hA);
  k_finalize<<<(NN + 63) / 64, 256, 0, stream>>>(mlp_w1, hA, xw);   // A in hA, B in xw
  k_emlp<<<(NN + 3) / 4, 256, 0, stream>>>(offs, csr, hA, xw, eattr,
                                           mlp_w1, mlp_b1, mlp_w2, mlp_b2, out);
}